// Round 1
// baseline (217.619 us; speedup 1.0000x reference)
//
#include <hip/hip_runtime.h>

// Problem constants (match reference)
#define Bq 8
#define Cq 128
#define Hq 128
#define Wq 256
#define Nq 1024
#define BN (Bq * Nq)

// e2 lambda = 2/7, e1 lambda = 1
// log(2*pi)
#define LOG_2PI 1.8378770664093453f
#define EPSq 1e-9f

// One block per sample (B*N = 8192 blocks), 128 threads = one channel each.
// Each thread gathers the 12-point neighborhood of fb for its channel,
// forms bilinear f_s, Jx, Jy, r and accumulates the 5 reduction values
// (Hxx, Hxy, Hyy, bx, by) across channels. Thread 0 finalizes the 2x2
// Gauss-Newton solve and writes per-sample e1 contribution and log(det)
// into the workspace (deterministic; no atomics).
__global__ __launch_bounds__(128) void gn_sample_kernel(
    const float* __restrict__ fb,
    const float* __restrict__ f_t,
    const float* __restrict__ ub,
    const float* __restrict__ noise,
    float* __restrict__ ws)
{
    const int n = blockIdx.x;          // sample index in [0, B*N)
    const int b = n >> 10;             // n / N  (N = 1024)
    const int c = threadIdx.x;         // channel

    // Sample coordinates (uniform across the block)
    const float ubx = ub[2 * n];
    const float uby = ub[2 * n + 1];
    const float xsx = ubx + noise[2 * n];
    const float xsy = uby + noise[2 * n + 1];

    float x = fminf(fmaxf(xsx, 0.0f), (float)(Wq - 1));
    float y = fminf(fmaxf(xsy, 0.0f), (float)(Hq - 1));
    int x0 = (int)floorf(x); x0 = min(max(x0, 0), Wq - 2);
    int y0 = (int)floorf(y); y0 = min(max(y0, 0), Hq - 2);
    const int x1 = x0 + 1, y1 = y0 + 1;
    const float wx = x - (float)x0;
    const float wy = y - (float)y0;

    // Gradient stencil indices (clamped) + scales: grad = (F[hi]-F[lo])/(hi-lo)
    const int xlo0 = max(x0 - 1, 0);           // for gx at x0 (hi = x1)
    const int xhi1 = min(x1 + 1, Wq - 1);      // for gx at x1 (lo = x0)
    const int ylo0 = max(y0 - 1, 0);           // for gy at y0 (hi = y1)
    const int yhi1 = min(y1 + 1, Hq - 1);      // for gy at y1 (lo = y0)
    const float sx0 = 1.0f / (float)(x1 - xlo0);
    const float sx1 = 1.0f / (float)(xhi1 - x0);
    const float sy0 = 1.0f / (float)(y1 - ylo0);
    const float sy1 = 1.0f / (float)(yhi1 - y0);

    const float* base = fb + (((size_t)b * Cq + c) * Hq) * Wq;
    const float* rlo = base + (size_t)ylo0 * Wq;
    const float* r0  = base + (size_t)y0  * Wq;
    const float* r1  = base + (size_t)y1  * Wq;
    const float* rhi = base + (size_t)yhi1 * Wq;

    // 12 gathered loads
    const float f_lo0 = rlo[x0], f_lo1 = rlo[x1];
    const float f0m = r0[xlo0], f00 = r0[x0], f01 = r0[x1], f0p = r0[xhi1];
    const float f1m = r1[xlo0], f10 = r1[x0], f11 = r1[x1], f1p = r1[xhi1];
    const float f_hi0 = rhi[x0], f_hi1 = rhi[x1];

    // gradients at the 4 corners
    const float gx00 = (f01 - f0m) * sx0;
    const float gx01 = (f0p - f00) * sx1;
    const float gx10 = (f11 - f1m) * sx0;
    const float gx11 = (f1p - f10) * sx1;
    const float gy00 = (f10 - f_lo0) * sy0;
    const float gy01 = (f11 - f_lo1) * sy0;
    const float gy10 = (f_hi0 - f00) * sy1;
    const float gy11 = (f_hi1 - f01) * sy1;

    // bilinear weights
    const float w00 = (1.0f - wx) * (1.0f - wy);
    const float w01 = wx * (1.0f - wy);
    const float w10 = (1.0f - wx) * wy;
    const float w11 = wx * wy;

    const float fs = f00 * w00 + f01 * w01 + f10 * w10 + f11 * w11;
    const float Jx = gx00 * w00 + gx01 * w01 + gx10 * w10 + gx11 * w11;
    const float Jy = gy00 * w00 + gy01 * w01 + gy10 * w10 + gy11 * w11;
    const float r  = fs - f_t[(size_t)n * Cq + c];

    float hxx = Jx * Jx;
    float hxy = Jx * Jy;
    float hyy = Jy * Jy;
    float bx  = Jx * r;
    float by  = Jy * r;

    // wave (64-lane) reduction
    #pragma unroll
    for (int off = 32; off > 0; off >>= 1) {
        hxx += __shfl_down(hxx, off);
        hxy += __shfl_down(hxy, off);
        hyy += __shfl_down(hyy, off);
        bx  += __shfl_down(bx, off);
        by  += __shfl_down(by, off);
    }
    __shared__ float red[2][5];
    const int wave = threadIdx.x >> 6;
    if ((threadIdx.x & 63) == 0) {
        red[wave][0] = hxx; red[wave][1] = hxy; red[wave][2] = hyy;
        red[wave][3] = bx;  red[wave][4] = by;
    }
    __syncthreads();
    if (threadIdx.x == 0) {
        const float A  = red[0][0] + red[1][0] + EPSq;   // Hm[0,0]
        const float Bv = red[0][1] + red[1][1];          // Hm[0,1] = Hm[1,0]
        const float D  = red[0][2] + red[1][2] + EPSq;   // Hm[1,1]
        const float bxs = red[0][3] + red[1][3];
        const float bys = red[0][4] + red[1][4];

        const float det = A * D - Bv * Bv;
        const float inv = 1.0f / det;
        // Hinv @ b
        const float hbx = ( D * bxs - Bv * bys) * inv;
        const float hby = (-Bv * bxs + A * bys) * inv;
        // diff = ub - miu = ub - (xs - Hinv b)
        const float dx = ubx - (xsx - hbx);
        const float dy = uby - (xsy - hby);
        const float quad = A * dx * dx + 2.0f * Bv * dx * dy + D * dy * dy;

        const float detc = fmaxf(det, 1e-16f);
        ws[n]      = 0.5f * quad;     // e1 contribution
        ws[BN + n] = logf(detc);      // log det contribution
    }
}

// Single-block final reduction -> (e, e1, e2)
__global__ __launch_bounds__(1024) void gn_reduce_kernel(
    const float* __restrict__ ws, float* __restrict__ out)
{
    float s1 = 0.0f, s2 = 0.0f;
    for (int i = threadIdx.x; i < BN; i += 1024) {
        s1 += ws[i];
        s2 += ws[BN + i];
    }
    #pragma unroll
    for (int off = 32; off > 0; off >>= 1) {
        s1 += __shfl_down(s1, off);
        s2 += __shfl_down(s2, off);
    }
    __shared__ float l1[16], l2[16];
    const int w = threadIdx.x >> 6;
    if ((threadIdx.x & 63) == 0) { l1[w] = s1; l2[w] = s2; }
    __syncthreads();
    if (threadIdx.x == 0) {
        float e1 = 0.0f, sl = 0.0f;
        #pragma unroll
        for (int i = 0; i < 16; ++i) { e1 += l1[i]; sl += l2[i]; }
        const float e2 = (float)BN * LOG_2PI - 0.5f * sl;
        out[0] = e1 + (2.0f / 7.0f) * e2;  // e
        out[1] = e1;
        out[2] = e2;
    }
}

extern "C" void kernel_launch(void* const* d_in, const int* in_sizes, int n_in,
                              void* d_out, int out_size, void* d_ws, size_t ws_size,
                              hipStream_t stream) {
    const float* fb    = (const float*)d_in[0];
    const float* f_t   = (const float*)d_in[1];
    const float* ub    = (const float*)d_in[2];
    const float* noise = (const float*)d_in[3];
    float* out = (float*)d_out;
    float* ws  = (float*)d_ws;   // needs 2 * B*N floats = 64 KiB

    gn_sample_kernel<<<BN, 128, 0, stream>>>(fb, f_t, ub, noise, ws);
    gn_reduce_kernel<<<1, 1024, 0, stream>>>(ws, out);
}